// Round 8
// baseline (67.517 us; speedup 1.0000x reference)
//
#include <hip/hip_runtime.h>
#include <hip/hip_bf16.h>

// SupConLoss fused: logits = text @ image^T (bf16 MFMA), masked two-sided
// logsumexp with fixed shift, softplus-mean -> scalar.
// B = N = 8192, D = 256, NUM_CLASSES = 64, T = 1.
//
// R8 = R7 + A-fragment register pinning. R7's VGPR_Count=64 proved the
// compiler rematerialized the afrag global loads inside the tile loop
// (~1.07 GB/launch of hidden L2 reads feeding the MFMA chain). The empty
// asm "+v" on each fragment forces true register residency (rule-17).
// Everything else identical to R7.

#define B_ROWS   8192
#define N_COLS   8192
#define DIM      256
#define CSPLIT   32                        // grid = (32, 32) = 1024 blocks
#define NTILES   ((N_COLS / CSPLIT) / 32)  // 8 col-tiles of 32 per block
#define BLK_ROWS 256                       // 8 waves x 32 rows
#define THREADS  512

typedef __attribute__((ext_vector_type(8))) short bf16x8;  // 8 bf16 = 4 VGPR
typedef __attribute__((ext_vector_type(4))) float f32x4;   // 16x16 MFMA acc

#if __has_builtin(__builtin_amdgcn_exp2f)
#define EXP2F(x) __builtin_amdgcn_exp2f(x)
#else
#define EXP2F(x) exp2f(x)
#endif
#if __has_builtin(__builtin_amdgcn_logf)
#define LOG2F(x) __builtin_amdgcn_logf(x)
#else
#define LOG2F(x) log2f(x)
#endif

__device__ __forceinline__ unsigned short f2bf(float f) {
    union { float f; unsigned u; } c; c.f = f;
    return (unsigned short)((c.u + 0x7FFFu + ((c.u >> 16) & 1u)) >> 16);
}

// One dispatch: zero gsum (16K floats), cvt A (row-major bf16), cvt+transpose
// B into Bt (the LDS chunk image).
// Bt: 256 groups (of 32 cols) x 16 KB. Within group g, chunk c (16 B) holds
// B[g*32 + (c&31)][k = (c>>5)*8 .. +8).
__global__ void cvt_all_kernel(const float* __restrict__ text,
                               const float* __restrict__ img,
                               unsigned short* __restrict__ Abf,
                               unsigned short* __restrict__ Bt,
                               float* __restrict__ gsum) {
    const int i = blockIdx.x * blockDim.x + threadIdx.x;   // [0, 524288)
    if (i < 4096) {   // 16384 floats = gsum_p[8192] ++ gsum_n[8192]
        reinterpret_cast<float4*>(gsum)[i] = float4{0.f, 0.f, 0.f, 0.f};
    }
    if (i < 262144) {
        // A: 8 consecutive f32 -> 8 bf16, coalesced
        const float4* src = reinterpret_cast<const float4*>(text) + i * 2;
        float4 v0 = src[0], v1 = src[1];
        unsigned short s[8];
        s[0] = f2bf(v0.x); s[1] = f2bf(v0.y); s[2] = f2bf(v0.z); s[3] = f2bf(v0.w);
        s[4] = f2bf(v1.x); s[5] = f2bf(v1.y); s[6] = f2bf(v1.z); s[7] = f2bf(v1.w);
        reinterpret_cast<bf16x8*>(Abf)[i] = *reinterpret_cast<const bf16x8*>(s);
    } else {
        const int C = i - 262144;           // Bt chunk id, [0, 262144)
        const int g = C >> 10, c = C & 1023;
        const int col = g * 32 + (c & 31);
        const int k8  = c >> 5;
        const float4* src =
            reinterpret_cast<const float4*>(img + (size_t)col * DIM + k8 * 8);
        float4 v0 = src[0], v1 = src[1];
        unsigned short s[8];
        s[0] = f2bf(v0.x); s[1] = f2bf(v0.y); s[2] = f2bf(v0.z); s[3] = f2bf(v0.w);
        s[4] = f2bf(v1.x); s[5] = f2bf(v1.y); s[6] = f2bf(v1.z); s[7] = f2bf(v1.w);
        reinterpret_cast<bf16x8*>(Bt)[C] = *reinterpret_cast<const bf16x8*>(s);
    }
}

// mfma_f32_16x16x32_bf16 layouts (R5-verified, absmax 0.0):
//   A: row = lane&15, k = 8*(lane>>4)+j
//   B: col = lane&15, k = 8*(lane>>4)+j
//   C: col = lane&15, row = (lane>>4)*4 + j
// LDS tile (16 KB): chunk c=(k8*32+col) at byte c*16.
// B-read addr: k8 = ks*4 + (lane>>4), col = ct*16 + (lane&15)
//   -> byte = ks*2048 + (lane>>4)*512 + ct*256 + (lane&15)*16.
__launch_bounds__(THREADS, 2)
__global__ void fused_gemm_lse(const unsigned short* __restrict__ Abf,
                               const unsigned short* __restrict__ Bt,
                               const int* __restrict__ tlab,
                               const int* __restrict__ itgt,
                               float* __restrict__ gsum_p,
                               float* __restrict__ gsum_n) {
    __shared__ char lds[16384] __attribute__((aligned(128)));

    const int tid  = threadIdx.x;
    const int lane = tid & 63;
    const int wave = tid >> 6;
    const int l15  = lane & 15;
    const int q    = lane >> 4;                  // quarter-wave (k-group)
    const int rb   = blockIdx.x * BLK_ROWS + wave * 32;  // 2 row-tiles
    const int cb0  = blockIdx.y * (N_COLS / CSPLIT);

    // A fragments for both row-tiles, all of K=256: 2 x 8 x 4 = 64 VGPR.
    bf16x8 afrag0[8], afrag1[8];
    const bf16x8* arow0 =
        reinterpret_cast<const bf16x8*>(Abf + (size_t)(rb + l15) * DIM) + q;
    const bf16x8* arow1 =
        reinterpret_cast<const bf16x8*>(Abf + (size_t)(rb + 16 + l15) * DIM) + q;
#pragma unroll
    for (int ks = 0; ks < 8; ++ks) {
        afrag0[ks] = arow0[ks * 4];
        afrag1[ks] = arow1[ks * 4];
    }
    // Pin the fragments in VGPRs: opaque redefinition forbids the compiler
    // from rematerializing the loads inside the tile loop (R7: VGPR=64 ->
    // afrags were re-loaded from L2 every tile, ~1 GB/launch hidden traffic).
#pragma unroll
    for (int ks = 0; ks < 8; ++ks) {
        asm volatile("" : "+v"(afrag0[ks]));
        asm volatile("" : "+v"(afrag1[ks]));
    }

    // Row classes of this thread's accumulator rows (2 row-tiles x 4 rows).
    int rowcls0[4], rowcls1[4];
#pragma unroll
    for (int j = 0; j < 4; ++j) {
        rowcls0[j] = tlab[rb + q * 4 + j];
        rowcls1[j] = tlab[rb + 16 + q * 4 + j];
    }

    float sump0[4] = {0, 0, 0, 0}, sumn0[4] = {0, 0, 0, 0};
    float sump1[4] = {0, 0, 0, 0}, sumn1[4] = {0, 0, 0, 0};

    // Staging: thread copies chunks tid and tid+512 (16 B each) per tile.
    const char* bsrc = (const char*)Bt
        + ((size_t)blockIdx.y * NTILES) * 16384 + tid * 16;
    char* ldsd = lds + tid * 16;

#define STAGE(T) do {                                                         \
    _Pragma("unroll")                                                         \
    for (int i_ = 0; i_ < 2; ++i_)                                            \
        __builtin_amdgcn_global_load_lds(                                     \
            (const __attribute__((address_space(1))) unsigned int*)           \
                (bsrc + (size_t)(T) * 16384 + i_ * 8192),                     \
            (__attribute__((address_space(3))) unsigned int*)                 \
                (ldsd + i_ * 8192),                                           \
            16, 0, 0);                                                        \
} while (0)

    const float L2E = 1.4426950408889634f;  // log2(e)
    const float C2  = 72.0f;                // fixed shift in log2 domain

    STAGE(0);
    int cc0 = itgt[cb0 + l15];
    int cc1 = itgt[cb0 + 16 + l15];

    for (int t = 0; t < NTILES; ++t) {
        __syncthreads();   // drains vmcnt -> tile t staged for all waves

        f32x4 acc00 = {0, 0, 0, 0}, acc01 = {0, 0, 0, 0};
        f32x4 acc10 = {0, 0, 0, 0}, acc11 = {0, 0, 0, 0};
        const char* bb = lds + q * 512 + l15 * 16;
#pragma unroll
        for (int ks = 0; ks < 8; ++ks) {
            bf16x8 b0 = *reinterpret_cast<const bf16x8*>(bb + ks * 2048);
            bf16x8 b1 = *reinterpret_cast<const bf16x8*>(bb + ks * 2048 + 256);
            acc00 = __builtin_amdgcn_mfma_f32_16x16x32_bf16(afrag0[ks], b0,
                                                            acc00, 0, 0, 0);
            acc01 = __builtin_amdgcn_mfma_f32_16x16x32_bf16(afrag0[ks], b1,
                                                            acc01, 0, 0, 0);
            acc10 = __builtin_amdgcn_mfma_f32_16x16x32_bf16(afrag1[ks], b0,
                                                            acc10, 0, 0, 0);
            acc11 = __builtin_amdgcn_mfma_f32_16x16x32_bf16(afrag1[ks], b1,
                                                            acc11, 0, 0, 0);
        }
        __syncthreads();   // all waves done reading before restage

        // Issue next tile's stage loads first, then do the epilogue VALU
        // while they are in flight (next __syncthreads drains them).
        if (t + 1 < NTILES) STAGE(t + 1);

        const int ncc0 = (t + 1 < NTILES) ? itgt[cb0 + (t + 1) * 32 + l15] : 0;
        const int ncc1 = (t + 1 < NTILES) ? itgt[cb0 + (t + 1) * 32 + 16 + l15] : 0;

#pragma unroll
        for (int j = 0; j < 4; ++j) {
            {
                const float x = acc00[j];
                const bool  p = (rowcls0[j] == cc0);
                const float e = EXP2F(__builtin_fmaf(x, p ? -L2E : L2E, -C2));
                sump0[j] += p ? e : 0.f;
                sumn0[j] += p ? 0.f : e;
            }
            {
                const float x = acc01[j];
                const bool  p = (rowcls0[j] == cc1);
                const float e = EXP2F(__builtin_fmaf(x, p ? -L2E : L2E, -C2));
                sump0[j] += p ? e : 0.f;
                sumn0[j] += p ? 0.f : e;
            }
            {
                const float x = acc10[j];
                const bool  p = (rowcls1[j] == cc0);
                const float e = EXP2F(__builtin_fmaf(x, p ? -L2E : L2E, -C2));
                sump1[j] += p ? e : 0.f;
                sumn1[j] += p ? 0.f : e;
            }
            {
                const float x = acc11[j];
                const bool  p = (rowcls1[j] == cc1);
                const float e = EXP2F(__builtin_fmaf(x, p ? -L2E : L2E, -C2));
                sump1[j] += p ? e : 0.f;
                sumn1[j] += p ? 0.f : e;
            }
        }
        cc0 = ncc0;
        cc1 = ncc1;
    }
#undef STAGE

    // Reduce over the 16 cols of each quarter-wave, then one atomic per row.
#pragma unroll
    for (int j = 0; j < 4; ++j) {
        float vp0 = sump0[j], vn0 = sumn0[j];
        float vp1 = sump1[j], vn1 = sumn1[j];
#pragma unroll
        for (int m = 1; m < 16; m <<= 1) {
            vp0 += __shfl_xor(vp0, m, 64);
            vn0 += __shfl_xor(vn0, m, 64);
            vp1 += __shfl_xor(vp1, m, 64);
            vn1 += __shfl_xor(vn1, m, 64);
        }
        if (l15 == 0) {
            const int row0 = rb + q * 4 + j;
            atomicAdd(&gsum_p[row0], vp0);
            atomicAdd(&gsum_n[row0], vn0);
            const int row1 = rb + 16 + q * 4 + j;
            atomicAdd(&gsum_p[row1], vp1);
            atomicAdd(&gsum_n[row1], vn1);
        }
    }
}

// lse_{p,n} = (log2(S) + C2) * ln2 ; loss = mean softplus(lse_p + lse_n)
__global__ void finalize_kernel(const float* __restrict__ gsum_p,
                                const float* __restrict__ gsum_n,
                                float* __restrict__ out) {
    __shared__ float red[1024];
    const float LN2 = 0.6931471805599453f;
    const float C2  = 72.0f;
    float acc = 0.f;
    for (int i = threadIdx.x; i < B_ROWS; i += 1024) {
        float zp = (LOG2F(gsum_p[i]) + C2) * LN2;
        float zn = (LOG2F(gsum_n[i]) + C2) * LN2;
        float z  = zp + zn;
        float sp = fmaxf(z, 0.f) + log1pf(expf(-fabsf(z)));
        acc += sp;
    }
    red[threadIdx.x] = acc;
    __syncthreads();
    for (int s = 512; s > 0; s >>= 1) {
        if ((int)threadIdx.x < s) red[threadIdx.x] += red[threadIdx.x + s];
        __syncthreads();
    }
    if (threadIdx.x == 0) out[0] = red[0] / (float)B_ROWS;
}

extern "C" void kernel_launch(void* const* d_in, const int* in_sizes, int n_in,
                              void* d_out, int out_size, void* d_ws, size_t ws_size,
                              hipStream_t stream) {
    const float* text = (const float*)d_in[0];   // [B, D] f32
    const float* img  = (const float*)d_in[1];   // [N, D] f32
    const int* tlab   = (const int*)d_in[2];     // [B]
    const int* itgt   = (const int*)d_in[3];     // [N]
    float* out        = (float*)d_out;           // scalar f32

    char* ws = (char*)d_ws;
    unsigned short* Abf = (unsigned short*)(ws);                            // 4 MB
    unsigned short* Bt  = (unsigned short*)(ws + (size_t)B_ROWS * DIM * 2); // 4 MB
    float* gsum_p = (float*)(ws + (size_t)(B_ROWS + N_COLS) * DIM * 2);
    float* gsum_n = gsum_p + B_ROWS;

    // One dispatch: zero gsum + cvt A + cvt/transpose B.
    cvt_all_kernel<<<(2 * 262144) / 256, 256, 0, stream>>>(text, img, Abf, Bt,
                                                           gsum_p);

    dim3 grid(B_ROWS / BLK_ROWS, CSPLIT);
    fused_gemm_lse<<<grid, THREADS, 0, stream>>>(Abf, Bt, tlab, itgt,
                                                 gsum_p, gsum_n);

    finalize_kernel<<<1, 1024, 0, stream>>>(gsum_p, gsum_n, out);
}